// Round 2
// baseline (170.964 us; speedup 1.0000x reference)
//
#include <hip/hip_runtime.h>
#include <hip/hip_bf16.h>
#include <math.h>

#define NB 32     // batch
#define NH 32     // query heads
#define HKV 8     // kv heads
#define GQ 4      // NH / HKV
#define DH 128    // head dim
#define BS 16     // paged block size
#define BPS 128   // blocks per seq
#define MAXC 2048 // max context (BPS * BS)
#define NSPLIT 8  // flash-decoding splits per (b, kvh)
#define TILE 32   // positions per LDS tile
#define PART_STRIDE 520  // per (b,kvh,split): 4 heads * (m, sum, acc[128])

__device__ __forceinline__ float bf16r(float x) {
    return __bfloat162float(__float2bfloat16(x));
}

// ---------------- Kernel A: RoPE q/k_new (bf16-cache-exact) -----------------
__global__ void rope_kernel(const float* __restrict__ q,
                            const float* __restrict__ knew,
                            const int* __restrict__ ctx,
                            float* __restrict__ q_rot,
                            float* __restrict__ k_rot)
{
    int b = blockIdx.x;
    int d = threadIdx.x;            // 0..127
    int pos = ctx[b];
    int i2 = d & 63;                // freq index (emb = concat(freqs,freqs))
    // Mimic: inv = bf16(1 / 10000^(i/64)), t = bf16(pos), fr = bf16(t*inv),
    //        cos/sin computed in f32 then rounded to bf16 (XLA bf16 semantics).
    float e  = (float)i2 * (1.0f / 64.0f);
    float pf = (float)pow(10000.0, (double)e);   // f32-rounded power
    float inv = bf16r(1.0f / pf);
    float tb  = bf16r((float)pos);
    float fr  = bf16r(tb * inv);
    float c   = bf16r(cosf(fr));
    float s   = bf16r(sinf(fr));

    const float* qb = q + (size_t)b * NH * DH;
    float* qo = q_rot + (size_t)b * NH * DH;
    #pragma unroll 4
    for (int h = 0; h < NH; ++h) {
        float x  = qb[h * DH + d];
        float xr = (d < 64) ? -qb[h * DH + d + 64] : qb[h * DH + d - 64];
        qo[h * DH + d] = x * c + xr * s;
    }
    const float* kb = knew + (size_t)b * HKV * DH;
    float* ko = k_rot + (size_t)b * HKV * DH;
    #pragma unroll
    for (int h = 0; h < HKV; ++h) {
        float x  = kb[h * DH + d];
        float xr = (d < 64) ? -kb[h * DH + d + 64] : kb[h * DH + d - 64];
        ko[h * DH + d] = x * c + xr * s;
    }
}

// ---------------- Kernel A2: resolve gather row -> source (scatter folded) --
// rowidx[b*MAXC + t] >= 0 : flat cache row; < 0 : -(j+1) -> new kv of batch j.
__global__ void rowidx_kernel(const int* __restrict__ bt,
                              const int* __restrict__ ctx,
                              int* __restrict__ rowidx)
{
    __shared__ int slot_l[NB];
    int tid = threadIdx.x;
    if (tid < NB) {
        int last = ctx[tid] - 1;
        slot_l[tid] = bt[tid * BPS + (last >> 4)] * BS + (last & 15);
    }
    __syncthreads();
    int g = blockIdx.x * 256 + tid;       // g = b*MAXC + t
    int b = g >> 11;
    int t = g & (MAXC - 1);
    int flat = bt[b * BPS + (t >> 4)] * BS + (t & 15);
    int o = flat;
    #pragma unroll
    for (int j = 0; j < NB; ++j)
        if (flat == slot_l[j]) o = -(j + 1);
    rowidx[g] = o;
}

// ---------------- Kernel B: attention partials (flash-decoding split) -------
__global__ __launch_bounds__(256) void attn_partial(
    const float* __restrict__ kc, const float* __restrict__ vc,
    const float* __restrict__ vnew,
    const int* __restrict__ ctx,
    const float* __restrict__ q_rot, const float* __restrict__ k_rot,
    const int* __restrict__ rowidx, float* __restrict__ part)
{
    // K/V tiles XOR-swizzled at float4 granularity: logical f4-col c of row r
    // lives at column (c ^ r). Balanced banks for stage, QK and PV patterns.
    __shared__ float q_lds[GQ][DH];
    __shared__ float k_lds[TILE][DH];
    __shared__ float v_lds[TILE][DH];
    __shared__ float p_lds[GQ][TILE];

    int tid = threadIdx.x;
    int bid = blockIdx.x;
    int sp  = bid & (NSPLIT - 1);
    int kvh = (bid / NSPLIT) & (HKV - 1);
    int b   = bid / (NSPLIT * HKV);

    int L = ctx[b];
    int chunk = (L + NSPLIT - 1) / NSPLIT;
    int start = sp * chunk;
    int end   = min(L, start + chunk);

    {   // stage q (4 heads x 128, contiguous)
        const float* qs = q_rot + ((size_t)b * NH + kvh * GQ) * DH;
        ((float*)q_lds)[tid]       = qs[tid];
        ((float*)q_lds)[tid + 256] = qs[tid + 256];
    }

    int lane = tid & 63;
    int h    = tid >> 6;      // wave == head group index (0..3)
    int l    = lane & 31;     // position within tile
    int half = lane >> 5;     // which 64-dim half of the dot
    int rr   = tid >> 5;      // staging base row (0..7)
    int c4   = tid & 31;      // staging f4 column

    float  m_run = -INFINITY;
    float  s_run = 0.0f;
    float2 acc   = make_float2(0.f, 0.f);

    float4 kreg[4], vreg[4];

    // prologue: prefetch first tile into registers
    #pragma unroll
    for (int i = 0; i < 4; ++i) {
        int r = rr + i * 8;
        int t = start + r;
        if (t < end) {
            int o = rowidx[(b << 11) | t];
            const float4 *ks, *vs;
            if (o >= 0) {
                size_t off = (size_t)o * (HKV * DH) + (size_t)kvh * DH;
                ks = (const float4*)(kc + off);
                vs = (const float4*)(vc + off);
            } else {
                int j = -o - 1;
                size_t off = ((size_t)j * HKV + kvh) * DH;
                ks = (const float4*)(k_rot + off);
                vs = (const float4*)(vnew + off);
            }
            kreg[i] = ks[c4];
            vreg[i] = vs[c4];
        }
    }
    __syncthreads();   // q_lds visible

    for (int t0 = start; t0 < end; t0 += TILE) {
        int n = min(TILE, end - t0);

        // write prefetched regs to LDS (compiler inserts the vmcnt wait here)
        #pragma unroll
        for (int i = 0; i < 4; ++i) {
            int r = rr + i * 8;
            if (t0 + r < end) {
                int sc = c4 ^ r;
                *(float4*)&k_lds[r][sc * 4] = kreg[i];
                *(float4*)&v_lds[r][sc * 4] = vreg[i];
            }
        }
        __syncthreads();

        // issue next tile's loads (land during compute below)
        int t1 = t0 + TILE;
        #pragma unroll
        for (int i = 0; i < 4; ++i) {
            int r = rr + i * 8;
            int t = t1 + r;
            if (t < end) {
                int o = rowidx[(b << 11) | t];
                const float4 *ks, *vs;
                if (o >= 0) {
                    size_t off = (size_t)o * (HKV * DH) + (size_t)kvh * DH;
                    ks = (const float4*)(kc + off);
                    vs = (const float4*)(vc + off);
                } else {
                    int j = -o - 1;
                    size_t off = ((size_t)j * HKV + kvh) * DH;
                    ks = (const float4*)(k_rot + off);
                    vs = (const float4*)(vnew + off);
                }
                kreg[i] = ks[c4];
                vreg[i] = vs[c4];
            }
        }

        // scores: lane (l, half) computes half-dot q[h] . K[l]
        float s = 0.f;
        if (l < n) {
            const float4* qrow = (const float4*)q_lds[h];
            #pragma unroll
            for (int k = 0; k < 16; ++k) {
                int j = half * 16 + k;
                float4 a  = qrow[j];
                float4 bb = *(const float4*)&k_lds[l][(j ^ l) * 4];
                s += a.x * bb.x + a.y * bb.y + a.z * bb.z + a.w * bb.w;
            }
        }
        s += __shfl_xor(s, 32);
        s *= 0.08838834764831845f;     // D^-0.5

        float sm = (l < n) ? s : -INFINITY;
        float tm = sm;
        #pragma unroll
        for (int off = 16; off >= 1; off >>= 1)
            tm = fmaxf(tm, __shfl_xor(tm, off));
        float mnew = fmaxf(m_run, tm);
        float p  = (l < n) ? expf(s - mnew) : 0.f;
        float ts = p;
        #pragma unroll
        for (int off = 16; off >= 1; off >>= 1)
            ts += __shfl_xor(ts, off);
        float r = expf(m_run - mnew);  // -inf - finite -> expf(-inf) = 0
        s_run = s_run * r + ts;
        m_run = mnew;
        acc.x *= r; acc.y *= r;
        // p_lds[h][*] is private to wave h; per-wave DS ops are in-order, so
        // no barrier between this write and the PV reads below.
        if (half == 0) p_lds[h][l] = p;

        // PV: lane owns d = lane*2, lane*2+1  (f4-col = lane>>1, sub = lane&1)
        int jc = lane >> 1, sub = lane & 1;
        for (int ll = 0; ll < n; ++ll) {
            float pv = p_lds[h][ll];
            const float2 vv = *(const float2*)&v_lds[ll][((jc ^ ll) << 2) + sub * 2];
            acc.x += pv * vv.x;
            acc.y += pv * vv.y;
        }
        __syncthreads();   // everyone done reading LDS before next ds_write
    }

    float* pp = part + (size_t)bid * PART_STRIDE + h * 130;
    if (lane == 0) { pp[0] = m_run; pp[1] = s_run; }
    *(float2*)&pp[2 + lane * 2] = acc;
}

// ---------------- Kernel C: combine split partials ---------------------------
__global__ void reduce_kernel(const float* __restrict__ part,
                              float* __restrict__ out)
{
    int blk = blockIdx.x;    // b*32 + h
    int d   = threadIdx.x;   // 0..127
    int b   = blk >> 5;
    int hq  = blk & 31;
    int kvh = hq >> 2;
    int g   = hq & 3;
    const float* base = part + ((size_t)(b * HKV + kvh) * NSPLIT) * PART_STRIDE + g * 130;

    float M = -INFINITY;
    #pragma unroll
    for (int s = 0; s < NSPLIT; ++s)
        M = fmaxf(M, base[(size_t)s * PART_STRIDE]);
    float S = 0.f, o = 0.f;
    #pragma unroll
    for (int s = 0; s < NSPLIT; ++s) {
        float ms = base[(size_t)s * PART_STRIDE];
        float f  = expf(ms - M);       // empty split: exp(-inf)=0
        S += base[(size_t)s * PART_STRIDE + 1] * f;
        o += base[(size_t)s * PART_STRIDE + 2 + d] * f;
    }
    out[(size_t)blk * DH + d] = o / S;
}

extern "C" void kernel_launch(void* const* d_in, const int* in_sizes, int n_in,
                              void* d_out, int out_size, void* d_ws, size_t ws_size,
                              hipStream_t stream)
{
    const float* q    = (const float*)d_in[0];
    const float* knew = (const float*)d_in[1];
    const float* vnew = (const float*)d_in[2];
    const float* kc   = (const float*)d_in[3];
    const float* vc   = (const float*)d_in[4];
    const int*   bt   = (const int*)d_in[5];
    const int*   ctx  = (const int*)d_in[6];
    float* out = (float*)d_out;

    float* ws     = (float*)d_ws;
    float* q_rot  = ws;                              // 32*32*128 = 131072 f
    float* k_rot  = ws + 131072;                     // 32*8*128  =  32768 f
    int*   rowidx = (int*)(ws + 131072 + 32768);     // 32*2048   =  65536 i
    float* part   = ws + 131072 + 32768 + 65536;     // 2048*520  = 1064960 f

    rope_kernel<<<NB, 128, 0, stream>>>(q, knew, ctx, q_rot, k_rot);
    rowidx_kernel<<<NB * MAXC / 256, 256, 0, stream>>>(bt, ctx, rowidx);
    attn_partial<<<NB * HKV * NSPLIT, 256, 0, stream>>>(
        kc, vc, vnew, ctx, q_rot, k_rot, rowidx, part);
    reduce_kernel<<<NB * NH, 128, 0, stream>>>(part, out);
}

// Round 3
// 78.616 us; speedup vs baseline: 2.1747x; 2.1747x over previous
//
#include <hip/hip_runtime.h>
#include <hip/hip_bf16.h>
#include <math.h>

#define NB 32     // batch
#define NH 32     // query heads
#define HKV 8     // kv heads
#define GQ 4      // NH / HKV
#define DH 128    // head dim
#define BS 16     // paged block size
#define BPS 128   // blocks per seq
#define MAXC 2048 // max context (BPS * BS)
#define NSPLIT 8  // flash-decoding splits per (b, kvh)
#define TILE 32   // positions per LDS tile
#define PART_STRIDE 520  // per (b,kvh,split): 4 heads * (m, sum, acc[128])

__device__ __forceinline__ float bf16r(float x) {
    return __bfloat162float(__float2bfloat16(x));
}

// ---------------- Kernel A: RoPE q/k_new (bf16-cache-exact) -----------------
__global__ void rope_kernel(const float* __restrict__ q,
                            const float* __restrict__ knew,
                            const int* __restrict__ ctx,
                            float* __restrict__ q_rot,
                            float* __restrict__ k_rot)
{
    int b = blockIdx.x;
    int d = threadIdx.x;            // 0..127
    int pos = ctx[b];
    int i2 = d & 63;                // freq index (emb = concat(freqs,freqs))
    // Mimic: inv = bf16(1 / 10000^(i/64)), t = bf16(pos), fr = bf16(t*inv),
    //        cos/sin computed in f32 then rounded to bf16 (XLA bf16 semantics).
    float e  = (float)i2 * (1.0f / 64.0f);
    float pf = (float)pow(10000.0, (double)e);   // f32-rounded power
    float inv = bf16r(1.0f / pf);
    float tb  = bf16r((float)pos);
    float fr  = bf16r(tb * inv);
    float c   = bf16r(cosf(fr));
    float s   = bf16r(sinf(fr));

    const float* qb = q + (size_t)b * NH * DH;
    float* qo = q_rot + (size_t)b * NH * DH;
    #pragma unroll 4
    for (int h = 0; h < NH; ++h) {
        float x  = qb[h * DH + d];
        float xr = (d < 64) ? -qb[h * DH + d + 64] : qb[h * DH + d - 64];
        qo[h * DH + d] = x * c + xr * s;
    }
    const float* kb = knew + (size_t)b * HKV * DH;
    float* ko = k_rot + (size_t)b * HKV * DH;
    #pragma unroll
    for (int h = 0; h < HKV; ++h) {
        float x  = kb[h * DH + d];
        float xr = (d < 64) ? -kb[h * DH + d + 64] : kb[h * DH + d - 64];
        ko[h * DH + d] = x * c + xr * s;
    }
}

// ---------------- Kernel A2: resolve gather row -> source (scatter folded) --
// rowidx[b*MAXC + t] >= 0 : flat cache row; < 0 : -(j+1) -> new kv of batch j.
__global__ void rowidx_kernel(const int* __restrict__ bt,
                              const int* __restrict__ ctx,
                              int* __restrict__ rowidx)
{
    __shared__ int slot_l[NB];
    int tid = threadIdx.x;
    if (tid < NB) {
        int last = ctx[tid] - 1;
        slot_l[tid] = bt[tid * BPS + (last >> 4)] * BS + (last & 15);
    }
    __syncthreads();
    int g = blockIdx.x * 256 + tid;       // g = b*MAXC + t
    int b = g >> 11;
    int t = g & (MAXC - 1);
    int flat = bt[b * BPS + (t >> 4)] * BS + (t & 15);
    int o = flat;
    #pragma unroll
    for (int j = 0; j < NB; ++j)
        if (flat == slot_l[j]) o = -(j + 1);
    rowidx[g] = o;
}

// ---------------- Kernel B: attention partials (flash-decoding split) -------
__global__ __launch_bounds__(256) void attn_partial(
    const float* __restrict__ kc, const float* __restrict__ vc,
    const float* __restrict__ vnew,
    const int* __restrict__ ctx,
    const float* __restrict__ q_rot, const float* __restrict__ k_rot,
    const int* __restrict__ rowidx, float* __restrict__ part)
{
    // K/V tiles XOR-swizzled at float4 granularity: logical f4-col c of row r
    // lives at column (c ^ r). Balanced banks for stage, QK and PV patterns.
    __shared__ float q_lds[GQ][DH];
    __shared__ float k_lds[TILE][DH];
    __shared__ float v_lds[TILE][DH];
    __shared__ float p_lds[GQ][TILE];

    int tid = threadIdx.x;
    int bid = blockIdx.x;
    int sp  = bid & (NSPLIT - 1);
    int kvh = (bid / NSPLIT) & (HKV - 1);
    int b   = bid / (NSPLIT * HKV);

    int L = ctx[b];
    int chunk = (L + NSPLIT - 1) / NSPLIT;
    int start = sp * chunk;
    int end   = min(L, start + chunk);

    {   // stage q (4 heads x 128, contiguous)
        const float* qs = q_rot + ((size_t)b * NH + kvh * GQ) * DH;
        ((float*)q_lds)[tid]       = qs[tid];
        ((float*)q_lds)[tid + 256] = qs[tid + 256];
    }

    int lane = tid & 63;
    int h    = tid >> 6;      // wave == head group index (0..3)
    int l    = lane & 31;     // position within tile
    int half = lane >> 5;     // which 64-dim half of the dot
    int rr   = tid >> 5;      // staging base row (0..7)
    int c4   = tid & 31;      // staging f4 column

    float  m_run = -INFINITY;
    float  s_run = 0.0f;
    float2 acc   = make_float2(0.f, 0.f);

    // Named prefetch registers (NO arrays -> no scratch demotion; round-2's
    // kreg[4]/vreg[4] arrays spilled: VGPR=52, 218 MB scratch traffic).
    float4 k0, k1, k2, k3, v0, v1, v2, v3;

    // Unconditional clamped gather: t clamped to end-1 (>=0 since L>=1);
    // garbage rows are never consumed (LDS write + compute stay guarded).
#define GATHER(T, KD, VD)                                                   \
    {                                                                        \
        int tt = min((T), end - 1);                                          \
        int o  = rowidx[(b << 11) | tt];                                     \
        int j  = -o - 1;                                                     \
        const float* kp = (o >= 0) ? kc + (size_t)o * (HKV * DH) + kvh * DH  \
                                   : k_rot + ((size_t)j * HKV + kvh) * DH;   \
        const float* vp = (o >= 0) ? vc + (size_t)o * (HKV * DH) + kvh * DH  \
                                   : vnew + ((size_t)j * HKV + kvh) * DH;    \
        KD = ((const float4*)kp)[c4];                                        \
        VD = ((const float4*)vp)[c4];                                        \
    }

#define PREFETCH(TB)                    \
    GATHER((TB) + rr,      k0, v0);     \
    GATHER((TB) + rr + 8,  k1, v1);     \
    GATHER((TB) + rr + 16, k2, v2);     \
    GATHER((TB) + rr + 24, k3, v3);

#define LDS_WRITE(TB)                                                        \
    {                                                                        \
        if ((TB) + rr < end) {                                               \
            int sc = (c4 ^ rr) * 4;                                          \
            *(float4*)&k_lds[rr][sc] = k0; *(float4*)&v_lds[rr][sc] = v0;    \
        }                                                                    \
        if ((TB) + rr + 8 < end) {                                           \
            int sc = (c4 ^ (rr + 8)) * 4;                                    \
            *(float4*)&k_lds[rr + 8][sc] = k1; *(float4*)&v_lds[rr + 8][sc] = v1; \
        }                                                                    \
        if ((TB) + rr + 16 < end) {                                          \
            int sc = (c4 ^ (rr + 16)) * 4;                                   \
            *(float4*)&k_lds[rr + 16][sc] = k2; *(float4*)&v_lds[rr + 16][sc] = v2; \
        }                                                                    \
        if ((TB) + rr + 24 < end) {                                          \
            int sc = (c4 ^ (rr + 24)) * 4;                                   \
            *(float4*)&k_lds[rr + 24][sc] = k3; *(float4*)&v_lds[rr + 24][sc] = v3; \
        }                                                                    \
    }

    PREFETCH(start);       // prologue: first tile into registers
    __syncthreads();       // q_lds visible

    for (int t0 = start; t0 < end; t0 += TILE) {
        int n = min(TILE, end - t0);

        LDS_WRITE(t0);     // compiler inserts the vmcnt wait here
        __syncthreads();

        PREFETCH(t0 + TILE);   // issue next tile's loads; land during compute

        // scores: lane (l, half) computes half-dot q[h] . K[l]
        float s = 0.f;
        if (l < n) {
            const float4* qrow = (const float4*)q_lds[h];
            #pragma unroll
            for (int k = 0; k < 16; ++k) {
                int j = half * 16 + k;
                float4 a  = qrow[j];
                float4 bb = *(const float4*)&k_lds[l][(j ^ l) * 4];
                s += a.x * bb.x + a.y * bb.y + a.z * bb.z + a.w * bb.w;
            }
        }
        s += __shfl_xor(s, 32);
        s *= 0.08838834764831845f;     // D^-0.5

        float sm = (l < n) ? s : -INFINITY;
        float tm = sm;
        #pragma unroll
        for (int off = 16; off >= 1; off >>= 1)
            tm = fmaxf(tm, __shfl_xor(tm, off));
        float mnew = fmaxf(m_run, tm);
        float p  = (l < n) ? expf(s - mnew) : 0.f;
        float ts = p;
        #pragma unroll
        for (int off = 16; off >= 1; off >>= 1)
            ts += __shfl_xor(ts, off);
        float r = expf(m_run - mnew);  // -inf - finite -> expf(-inf) = 0
        s_run = s_run * r + ts;
        m_run = mnew;
        acc.x *= r; acc.y *= r;
        // p_lds[h][*] is private to wave h; per-wave DS ops are in-order, so
        // no barrier between this write and the PV reads below.
        if (half == 0) p_lds[h][l] = p;

        // PV: lane owns d = lane*2, lane*2+1  (f4-col = lane>>1, sub = lane&1)
        int jc = lane >> 1, sub = lane & 1;
        for (int ll = 0; ll < n; ++ll) {
            float pv = p_lds[h][ll];
            const float2 vv = *(const float2*)&v_lds[ll][((jc ^ ll) << 2) + sub * 2];
            acc.x += pv * vv.x;
            acc.y += pv * vv.y;
        }
        __syncthreads();   // everyone done reading LDS before next ds_write
    }

    float* pp = part + (size_t)bid * PART_STRIDE + h * 130;
    if (lane == 0) { pp[0] = m_run; pp[1] = s_run; }
    *(float2*)&pp[2 + lane * 2] = acc;
}

// ---------------- Kernel C: combine split partials ---------------------------
__global__ void reduce_kernel(const float* __restrict__ part,
                              float* __restrict__ out)
{
    int blk = blockIdx.x;    // b*32 + h
    int d   = threadIdx.x;   // 0..127
    int b   = blk >> 5;
    int hq  = blk & 31;
    int kvh = hq >> 2;
    int g   = hq & 3;
    const float* base = part + ((size_t)(b * HKV + kvh) * NSPLIT) * PART_STRIDE + g * 130;

    float M = -INFINITY;
    #pragma unroll
    for (int s = 0; s < NSPLIT; ++s)
        M = fmaxf(M, base[(size_t)s * PART_STRIDE]);
    float S = 0.f, o = 0.f;
    #pragma unroll
    for (int s = 0; s < NSPLIT; ++s) {
        float ms = base[(size_t)s * PART_STRIDE];
        float f  = expf(ms - M);       // empty split: exp(-inf)=0
        S += base[(size_t)s * PART_STRIDE + 1] * f;
        o += base[(size_t)s * PART_STRIDE + 2 + d] * f;
    }
    out[(size_t)blk * DH + d] = o / S;
}

extern "C" void kernel_launch(void* const* d_in, const int* in_sizes, int n_in,
                              void* d_out, int out_size, void* d_ws, size_t ws_size,
                              hipStream_t stream)
{
    const float* q    = (const float*)d_in[0];
    const float* knew = (const float*)d_in[1];
    const float* vnew = (const float*)d_in[2];
    const float* kc   = (const float*)d_in[3];
    const float* vc   = (const float*)d_in[4];
    const int*   bt   = (const int*)d_in[5];
    const int*   ctx  = (const int*)d_in[6];
    float* out = (float*)d_out;

    float* ws     = (float*)d_ws;
    float* q_rot  = ws;                              // 32*32*128 = 131072 f
    float* k_rot  = ws + 131072;                     // 32*8*128  =  32768 f
    int*   rowidx = (int*)(ws + 131072 + 32768);     // 32*2048   =  65536 i
    float* part   = ws + 131072 + 32768 + 65536;     // 2048*520  = 1064960 f

    rope_kernel<<<NB, 128, 0, stream>>>(q, knew, ctx, q_rot, k_rot);
    rowidx_kernel<<<NB * MAXC / 256, 256, 0, stream>>>(bt, ctx, rowidx);
    attn_partial<<<NB * HKV * NSPLIT, 256, 0, stream>>>(
        kc, vc, vnew, ctx, q_rot, k_rot, rowidx, part);
    reduce_kernel<<<NB * NH, 128, 0, stream>>>(part, out);
}